// Round 6
// baseline (283.528 us; speedup 1.0000x reference)
//
#include <hip/hip_runtime.h>
#include <stdint.h>
#include <stddef.h>

#define B_ 8
#define L_ 2048
#define D_ 256
#define KSPLIT 4
#define KRANGE 512
#define KTILE 32
#define NITER 16    // KRANGE / KTILE
#define PSS 40

typedef __bf16 bf16x8 __attribute__((ext_vector_type(8)));
typedef float floatx4 __attribute__((ext_vector_type(4)));
typedef _Float16 half4_t __attribute__((ext_vector_type(4)));

__device__ __forceinline__ short f2bf(float f) {
    union { float f; uint32_t u; } v; v.f = f;
    return (short)((v.u + 0x8000u) >> 16);
}

__device__ __forceinline__ uint32_t pack2bf(float a, float b) {
    union { float f; uint32_t u; } x, y; x.f = a; y.f = b;
    return ((x.u + 0x8000u) >> 16) | ((y.u + 0x8000u) & 0xFFFF0000u);
}

__device__ __forceinline__ void async16(const void* g, void* l) {
    __builtin_amdgcn_global_load_lds(
        (__attribute__((address_space(1))) void*)g,
        (__attribute__((address_space(3))) void*)l,
        16, 0, 0);
}

// ---------------------------------------------------------------------------
// prep: blocks 0..255 proj-q, 256..511 proj-k, 512..1023 vtrans. One dispatch
// so the three independent jobs overlap instead of serializing.
// ---------------------------------------------------------------------------
__global__ __launch_bounds__(256, 3) void prep_kernel(
    const float* __restrict__ Xq, const float* __restrict__ Xk,
    const float* __restrict__ V,
    const float* __restrict__ Wq, const float* __restrict__ Wk,
    const float* __restrict__ bq, const float* __restrict__ bk,
    short* __restrict__ Oq, short* __restrict__ Ok, short* __restrict__ Vt)
{
    __shared__ uint32_t sm[12800];   // 51.2 KB pool
    const int tid  = threadIdx.x;
    const int pid  = blockIdx.x;

    if (pid < 512) {
        // ---------------- projection ----------------
        const int sel = pid >> 8;
        const float* X    = sel ? Xk : Xq;
        const float* W    = sel ? Wk : Wq;
        const float* bias = sel ? bk : bq;
        short* Out        = sel ? Ok : Oq;

        const int wid  = tid >> 6;
        const int lane = tid & 63;
        const int m16  = lane & 15;
        const int quad = lane >> 4;
        const int row0 = (pid & 255) * 64;
        const int ar = tid >> 2, cg = tid & 3;

        floatx4 acc[16];
        const floatx4 z4 = {0.f, 0.f, 0.f, 0.f};
#pragma unroll
        for (int i = 0; i < 16; i++) acc[i] = z4;

        {
            const float* srcA = X + (size_t)(row0 + ar) * D_ + cg * 8;
            float4 a = *(const float4*)srcA, b2 = *(const float4*)(srcA + 4);
            uint4 u; u.x = pack2bf(a.x, a.y); u.y = pack2bf(a.z, a.w);
            u.z = pack2bf(b2.x, b2.y); u.w = pack2bf(b2.z, b2.w);
            *(uint4*)&sm[ar * 20 + cg * 4] = u;
#pragma unroll
            for (int p = 0; p < 4; p++) {
                const float* srcW = W + (size_t)(p * 64 + ar) * D_ + cg * 8;
                float4 wa = *(const float4*)srcW, wb = *(const float4*)(srcW + 4);
                uint4 w; w.x = pack2bf(wa.x, wa.y); w.y = pack2bf(wa.z, wa.w);
                w.z = pack2bf(wb.x, wb.y); w.w = pack2bf(wb.z, wb.w);
                *(uint4*)&sm[2560 + (p * 64 + ar) * 20 + cg * 4] = w;
            }
        }
        __syncthreads();

        for (int kc = 0; kc < 8; kc++) {
            const int buf = kc & 1;
            uint32_t* Ab = sm + buf * 1280;
            uint32_t* Wb = sm + 2560 + buf * 5120;
            float4 na, nb, nwa[4], nwb[4];
            if (kc < 7) {
                const int k1 = (kc + 1) * 32;
                const float* srcA = X + (size_t)(row0 + ar) * D_ + k1 + cg * 8;
                na = *(const float4*)srcA; nb = *(const float4*)(srcA + 4);
#pragma unroll
                for (int p = 0; p < 4; p++) {
                    const float* srcW = W + (size_t)(p * 64 + ar) * D_ + k1 + cg * 8;
                    nwa[p] = *(const float4*)srcW; nwb[p] = *(const float4*)(srcW + 4);
                }
            }
            bf16x8 af = *(const bf16x8*)&Ab[(wid * 16 + m16) * 20 + quad * 4];
#pragma unroll
            for (int n = 0; n < 16; n++) {
                bf16x8 bfr = *(const bf16x8*)&Wb[(n * 16 + m16) * 20 + quad * 4];
                acc[n] = __builtin_amdgcn_mfma_f32_16x16x32_bf16(af, bfr, acc[n], 0, 0, 0);
            }
            if (kc < 7) {
                uint32_t* An = sm + (buf ^ 1) * 1280;
                uint32_t* Wn = sm + 2560 + (buf ^ 1) * 5120;
                uint4 u; u.x = pack2bf(na.x, na.y); u.y = pack2bf(na.z, na.w);
                u.z = pack2bf(nb.x, nb.y); u.w = pack2bf(nb.z, nb.w);
                *(uint4*)&An[ar * 20 + cg * 4] = u;
#pragma unroll
                for (int p = 0; p < 4; p++) {
                    uint4 w; w.x = pack2bf(nwa[p].x, nwa[p].y); w.y = pack2bf(nwa[p].z, nwa[p].w);
                    w.z = pack2bf(nwb[p].x, nwb[p].y); w.w = pack2bf(nwb[p].z, nwb[p].w);
                    *(uint4*)&Wn[(p * 64 + ar) * 20 + cg * 4] = w;
                }
            }
            __syncthreads();
        }
#pragma unroll
        for (int n = 0; n < 16; n++) {
            const int col = n * 16 + m16;
            const float bv = bias[col];
#pragma unroll
            for (int r = 0; r < 4; r++) {
                const int row = row0 + wid * 16 + quad * 4 + r;
                Out[(size_t)row * D_ + col] = f2bf(acc[n][r] + bv);
            }
        }
    } else {
        // ---------------- V transpose ----------------
        uint32_t* T = sm;                 // 256*20 uints
        const int vb = pid - 512;
        const int b  = vb >> 6;
        const int l0 = (vb & 63) * 32;
        const int r2 = tid >> 4;
        const int dg = tid & 15;
        const int lp = r2 ^ ((dg & 3) << 2);
#pragma unroll
        for (int p = 0; p < 4; p++) {
            int d0 = (dg + p * 16) * 4;
            const float* src = V + ((size_t)b * L_ + l0 + r2 * 2) * D_ + d0;
            float4 e0 = *(const float4*)src;
            float4 e1 = *(const float4*)(src + D_);
            T[(d0 + 0) * 20 + lp] = pack2bf(e0.x, e1.x);
            T[(d0 + 1) * 20 + lp] = pack2bf(e0.y, e1.y);
            T[(d0 + 2) * 20 + lp] = pack2bf(e0.z, e1.z);
            T[(d0 + 3) * 20 + lp] = pack2bf(e0.w, e1.w);
        }
        __syncthreads();
#pragma unroll
        for (int p = 0; p < 4; p++) {
            int d = (tid >> 2) + p * 64;
            int c = tid & 3;
            int cp = c ^ ((d >> 2) & 3);
            uint4 u = *(const uint4*)&T[d * 20 + cp * 4];
            *(uint4*)(Vt + ((size_t)b * D_ + d) * L_ + l0 + c * 8) = u;
        }
    }
}

// ---------------------------------------------------------------------------
// Flash: q-tile 64, 4 waves. QK: wave = 32q x 16k-slice (Q in regs, K in LDS
// dbuf). PV: wave = 32q x 128d-half, V-frags direct from global (L2).
// Ps double-buffered in LDS, one barrier/iter. 3 waves/SIMD, 3 blocks/CU.
// ---------------------------------------------------------------------------
__global__ __launch_bounds__(256, 3) void flash_kernel(
    const short* __restrict__ Qb, const short* __restrict__ Kb,
    const short* __restrict__ Vt, const int* __restrict__ mask,
    float* __restrict__ Out, _Float16* __restrict__ Part,
    float* __restrict__ Lpart)
{
    __shared__ short Ks[2][KTILE * 256];   // 2 x 16 KB
    __shared__ short Ps[2][64 * PSS];      // 2 x 5 KB
    __shared__ float Lred[64];

    const int tid  = threadIdx.x;
    const int wid  = tid >> 6;
    const int lane = tid & 63;
    const int m16  = lane & 15;
    const int quad = lane >> 4;
    const int b  = blockIdx.x;
    const int q0 = blockIdx.y * 64;
    const int z  = blockIdx.z;

    const int qr  = (wid & 1) * 32;    // q-range base (QK and PV)
    const int ksl = (wid >> 1) * 16;   // k-slice within KTILE (QK)
    const int dh  = (wid >> 1) * 128;  // d-half (PV)

    const short* kbase = Kb + ((size_t)b * L_ + z * KRANGE) * D_;
    const short* vbase = Vt + (size_t)b * D_ * L_ + (size_t)z * KRANGE;
    const int*   mg    = mask + b * L_ + z * KRANGE;

    // Q: 32 rows x 256 d in registers (A-fragments)
    bf16x8 qf[2][8];
    {
        const short* qrow = Qb + ((size_t)b * L_ + q0 + qr) * D_;
#pragma unroll
        for (int s2 = 0; s2 < 2; s2++)
#pragma unroll
            for (int kk = 0; kk < 8; kk++)
                qf[s2][kk] = *(const bf16x8*)(qrow + (size_t)(s2 * 16 + m16) * D_ + kk * 32 + quad * 8);
    }

    floatx4 o[2][8];
    const floatx4 z4 = {0.f, 0.f, 0.f, 0.f};
#pragma unroll
    for (int s2 = 0; s2 < 2; s2++)
#pragma unroll
        for (int dt = 0; dt < 8; dt++) o[s2][dt] = z4;
    float rs[2][4] = {{0.f,0.f,0.f,0.f},{0.f,0.f,0.f,0.f}};

    auto stageK = [&](int t, int bufi) {
#pragma unroll
        for (int c = 0; c < 4; c++) {
            int unit = wid * 4 + c;              // 16 units x 1 KB
            int row = unit * 2 + (lane >> 5);
            int g = (lane & 31) ^ (row & 7);
            async16(kbase + (size_t)(t * KTILE + row) * D_ + g * 8,
                    &Ks[bufi][unit * 512]);
        }
    };

    stageK(0, 0);
    __builtin_amdgcn_s_waitcnt(0x0F70);  // vmcnt(0)
    __syncthreads();

    const float C2 = 0.09016844f;        // log2(e)/16

    for (int t = 0; t < NITER; t++) {
        const int buf = t & 1;
        if (t + 1 < NITER) stageK(t + 1, buf ^ 1);

        // ---- QK(t): 32q x 16k slice ----
        const short* kl = &Ks[buf][0];
        floatx4 s[2] = { z4, z4 };
#pragma unroll
        for (int kk = 0; kk < 8; kk++) {
            int lc = (kk * 4 + quad) ^ (m16 & 7);
            bf16x8 kf = *(const bf16x8*)(kl + (ksl + m16) * 256 + lc * 8);
            s[0] = __builtin_amdgcn_mfma_f32_16x16x32_bf16(qf[0][kk], kf, s[0], 0, 0, 0);
            s[1] = __builtin_amdgcn_mfma_f32_16x16x32_bf16(qf[1][kk], kf, s[1], 0, 0, 0);
        }

        // ---- softmax piece: P = exp2(S*C2 + moff) ----
        const int mv = mg[t * KTILE + ksl + m16];
        const float moff = mv ? 0.f : -1.0e30f;
        short* psw = &Ps[buf][0];
#pragma unroll
        for (int s2 = 0; s2 < 2; s2++)
#pragma unroll
            for (int r = 0; r < 4; r++) {
                float p = exp2f(fmaf(s[s2][r], C2, moff));
                rs[s2][r] += p;
                psw[(qr + s2 * 16 + quad * 4 + r) * PSS + ksl + m16] = f2bf(p);
            }

        __syncthreads();   // P(t) visible to all waves; also drains K-DMA

        // ---- PV(t): 32q x 128d-half, V from global (L2) ----
        bf16x8 pa[2];
#pragma unroll
        for (int s2 = 0; s2 < 2; s2++)
            pa[s2] = *(const bf16x8*)(psw + (qr + s2 * 16 + m16) * PSS + quad * 8);
#pragma unroll
        for (int g2 = 0; g2 < 2; g2++) {
            bf16x8 vf[4];
#pragma unroll
            for (int i = 0; i < 4; i++) {
                int d = dh + (g2 * 4 + i) * 16 + m16;
                vf[i] = *(const bf16x8*)(vbase + (size_t)d * L_ + t * KTILE + quad * 8);
            }
#pragma unroll
            for (int i = 0; i < 4; i++) {
                o[0][g2 * 4 + i] = __builtin_amdgcn_mfma_f32_16x16x32_bf16(pa[0], vf[i], o[0][g2 * 4 + i], 0, 0, 0);
                o[1][g2 * 4 + i] = __builtin_amdgcn_mfma_f32_16x16x32_bf16(pa[1], vf[i], o[1][g2 * 4 + i], 0, 0, 0);
            }
        }
    }

    // ---- row-sum: reduce across m16 lanes, then across wave pairs ----
#pragma unroll
    for (int s2 = 0; s2 < 2; s2++)
#pragma unroll
        for (int r = 0; r < 4; r++) {
            float x = rs[s2][r];
            x += __shfl_xor(x, 1, 16);
            x += __shfl_xor(x, 2, 16);
            x += __shfl_xor(x, 4, 16);
            x += __shfl_xor(x, 8, 16);
            rs[s2][r] = x;
        }
    if (wid >= 2 && m16 == 0) {
#pragma unroll
        for (int s2 = 0; s2 < 2; s2++)
#pragma unroll
            for (int r = 0; r < 4; r++)
                Lred[qr + s2 * 16 + quad * 4 + r] = rs[s2][r];
    }
    __syncthreads();
    if (wid < 2 && m16 == 0) {
#pragma unroll
        for (int s2 = 0; s2 < 2; s2++)
#pragma unroll
            for (int r = 0; r < 4; r++) {
                float l = rs[s2][r] + Lred[qr + s2 * 16 + quad * 4 + r];
                Lpart[(size_t)z * (B_ * L_) + (size_t)b * L_ + q0 + qr + s2 * 16 + quad * 4 + r] = l;
            }
    }

    // ---- store partial O (unnormalized) ----
    const size_t BLD = (size_t)B_ * L_ * D_;
    const size_t rowb = (size_t)b * L_ + q0 + qr;
    if (z == 0) {
        float* po = Out + rowb * D_ + dh;
#pragma unroll
        for (int s2 = 0; s2 < 2; s2++)
#pragma unroll
            for (int dt = 0; dt < 8; dt++)
#pragma unroll
                for (int r = 0; r < 4; r++)
                    po[(size_t)(s2 * 16 + quad * 4 + r) * D_ + dt * 16 + m16] = o[s2][dt][r];
    } else {
        _Float16* pp = Part + (size_t)(z - 1) * BLD + rowb * D_ + dh;
#pragma unroll
        for (int s2 = 0; s2 < 2; s2++)
#pragma unroll
            for (int dt = 0; dt < 8; dt++)
#pragma unroll
                for (int r = 0; r < 4; r++)
                    pp[(size_t)(s2 * 16 + quad * 4 + r) * D_ + dt * 16 + m16] = (_Float16)o[s2][dt][r];
    }
}

// ---------------------------------------------------------------------------
// Normalize: out = (P0_f32 + P1..3_f16) / (l0+l1+l2+l3)
// ---------------------------------------------------------------------------
__global__ __launch_bounds__(256) void norm_kernel(
    float* __restrict__ Out, const _Float16* __restrict__ Part,
    const float* __restrict__ Lpart)
{
    const int idx = blockIdx.x * 256 + threadIdx.x;
    const int row = idx >> 6;
    const int c   = (idx & 63) * 4;
    const size_t off = (size_t)row * D_ + c;
    const size_t BLD = (size_t)B_ * L_ * D_;
    float4 acc = *(float4*)(Out + off);
#pragma unroll
    for (int zz = 0; zz < 3; zz++) {
        half4_t h = *(const half4_t*)(Part + zz * BLD + off);
        acc.x += (float)h.x; acc.y += (float)h.y;
        acc.z += (float)h.z; acc.w += (float)h.w;
    }
    const int BL = B_ * L_;
    float l = Lpart[row] + Lpart[BL + row] + Lpart[2 * BL + row] + Lpart[3 * BL + row];
    float inv = 1.0f / l;
    acc.x *= inv; acc.y *= inv; acc.z *= inv; acc.w *= inv;
    *(float4*)(Out + off) = acc;
}

extern "C" void kernel_launch(void* const* d_in, const int* in_sizes, int n_in,
                              void* d_out, int out_size, void* d_ws, size_t ws_size,
                              hipStream_t stream) {
    const float* query = (const float*)d_in[0];
    const float* key   = (const float*)d_in[1];
    const float* value = (const float*)d_in[2];
    const int*   mask  = (const int*)d_in[3];
    const float* Wq_w  = (const float*)d_in[4];
    const float* Wq_b  = (const float*)d_in[5];
    const float* Wk_w  = (const float*)d_in[6];
    const float* Wk_b  = (const float*)d_in[7];
    float* out = (float*)d_out;

    const size_t BLD = (size_t)B_ * L_ * D_;
    short* qb = (short*)d_ws;
    short* kb = qb + BLD;
    short* vt = kb + BLD;
    _Float16* part = (_Float16*)(vt + BLD);
    float* lpart = (float*)(part + 3 * BLD);

    prep_kernel<<<dim3(1024), 256, 0, stream>>>(query, key, value, Wq_w, Wk_w,
                                                Wq_b, Wk_b, qb, kb, vt);
    flash_kernel<<<dim3(8, 32, 4), 256, 0, stream>>>(qb, kb, vt, mask, out, part, lpart);
    norm_kernel<<<dim3((B_ * L_ * D_ / 4) / 256), 256, 0, stream>>>(out, part, lpart);
}

// Round 7
// 265.003 us; speedup vs baseline: 1.0699x; 1.0699x over previous
//
#include <hip/hip_runtime.h>
#include <stdint.h>
#include <stddef.h>

#define B_ 8
#define L_ 2048
#define D_ 256
#define KSPLIT 4
#define KRANGE 512
#define KTILE 32
#define NITER 16    // KRANGE / KTILE
#define PSS 40

typedef __bf16 bf16x8 __attribute__((ext_vector_type(8)));
typedef float floatx4 __attribute__((ext_vector_type(4)));
typedef _Float16 half4_t __attribute__((ext_vector_type(4)));

__device__ __forceinline__ short f2bf(float f) {
    union { float f; uint32_t u; } v; v.f = f;
    return (short)((v.u + 0x8000u) >> 16);
}

__device__ __forceinline__ uint32_t pack2bf(float a, float b) {
    union { float f; uint32_t u; } x, y; x.f = a; y.f = b;
    return ((x.u + 0x8000u) >> 16) | ((y.u + 0x8000u) & 0xFFFF0000u);
}

__device__ __forceinline__ void async16(const void* g, void* l) {
    __builtin_amdgcn_global_load_lds(
        (__attribute__((address_space(1))) void*)g,
        (__attribute__((address_space(3))) void*)l,
        16, 0, 0);
}

// ---------------------------------------------------------------------------
// prep: blocks 0..255 proj-q, 256..511 proj-k, 512..767 vtrans (2 tiles each).
// 768 blocks = exactly 3/CU, one residency round.
// ---------------------------------------------------------------------------
__global__ __launch_bounds__(256, 3) void prep_kernel(
    const float* __restrict__ Xq, const float* __restrict__ Xk,
    const float* __restrict__ V,
    const float* __restrict__ Wq, const float* __restrict__ Wk,
    const float* __restrict__ bq, const float* __restrict__ bk,
    short* __restrict__ Oq, short* __restrict__ Ok, short* __restrict__ Vt)
{
    __shared__ uint32_t sm[12800];   // 51.2 KB pool
    const int tid  = threadIdx.x;
    const int pid  = blockIdx.x;

    if (pid < 512) {
        // ---------------- projection ----------------
        const int sel = pid >> 8;
        const float* X    = sel ? Xk : Xq;
        const float* W    = sel ? Wk : Wq;
        const float* bias = sel ? bk : bq;
        short* Out        = sel ? Ok : Oq;

        const int wid  = tid >> 6;
        const int lane = tid & 63;
        const int m16  = lane & 15;
        const int quad = lane >> 4;
        const int row0 = (pid & 255) * 64;
        const int ar = tid >> 2, cg = tid & 3;

        floatx4 acc[16];
        const floatx4 z4 = {0.f, 0.f, 0.f, 0.f};
#pragma unroll
        for (int i = 0; i < 16; i++) acc[i] = z4;

        {
            const float* srcA = X + (size_t)(row0 + ar) * D_ + cg * 8;
            float4 a = *(const float4*)srcA, b2 = *(const float4*)(srcA + 4);
            uint4 u; u.x = pack2bf(a.x, a.y); u.y = pack2bf(a.z, a.w);
            u.z = pack2bf(b2.x, b2.y); u.w = pack2bf(b2.z, b2.w);
            *(uint4*)&sm[ar * 20 + cg * 4] = u;
#pragma unroll
            for (int p = 0; p < 4; p++) {
                const float* srcW = W + (size_t)(p * 64 + ar) * D_ + cg * 8;
                float4 wa = *(const float4*)srcW, wb = *(const float4*)(srcW + 4);
                uint4 w; w.x = pack2bf(wa.x, wa.y); w.y = pack2bf(wa.z, wa.w);
                w.z = pack2bf(wb.x, wb.y); w.w = pack2bf(wb.z, wb.w);
                *(uint4*)&sm[2560 + (p * 64 + ar) * 20 + cg * 4] = w;
            }
        }
        __syncthreads();

        for (int kc = 0; kc < 8; kc++) {
            const int buf = kc & 1;
            uint32_t* Ab = sm + buf * 1280;
            uint32_t* Wb = sm + 2560 + buf * 5120;
            float4 na, nb, nwa[4], nwb[4];
            if (kc < 7) {
                const int k1 = (kc + 1) * 32;
                const float* srcA = X + (size_t)(row0 + ar) * D_ + k1 + cg * 8;
                na = *(const float4*)srcA; nb = *(const float4*)(srcA + 4);
#pragma unroll
                for (int p = 0; p < 4; p++) {
                    const float* srcW = W + (size_t)(p * 64 + ar) * D_ + k1 + cg * 8;
                    nwa[p] = *(const float4*)srcW; nwb[p] = *(const float4*)(srcW + 4);
                }
            }
            bf16x8 af = *(const bf16x8*)&Ab[(wid * 16 + m16) * 20 + quad * 4];
#pragma unroll
            for (int n = 0; n < 16; n++) {
                bf16x8 bfr = *(const bf16x8*)&Wb[(n * 16 + m16) * 20 + quad * 4];
                acc[n] = __builtin_amdgcn_mfma_f32_16x16x32_bf16(af, bfr, acc[n], 0, 0, 0);
            }
            if (kc < 7) {
                uint32_t* An = sm + (buf ^ 1) * 1280;
                uint32_t* Wn = sm + 2560 + (buf ^ 1) * 5120;
                uint4 u; u.x = pack2bf(na.x, na.y); u.y = pack2bf(na.z, na.w);
                u.z = pack2bf(nb.x, nb.y); u.w = pack2bf(nb.z, nb.w);
                *(uint4*)&An[ar * 20 + cg * 4] = u;
#pragma unroll
                for (int p = 0; p < 4; p++) {
                    uint4 w; w.x = pack2bf(nwa[p].x, nwa[p].y); w.y = pack2bf(nwa[p].z, nwa[p].w);
                    w.z = pack2bf(nwb[p].x, nwb[p].y); w.w = pack2bf(nwb[p].z, nwb[p].w);
                    *(uint4*)&Wn[(p * 64 + ar) * 20 + cg * 4] = w;
                }
            }
            __syncthreads();
        }
#pragma unroll
        for (int n = 0; n < 16; n++) {
            const int col = n * 16 + m16;
            const float bv = bias[col];
#pragma unroll
            for (int r = 0; r < 4; r++) {
                const int row = row0 + wid * 16 + quad * 4 + r;
                Out[(size_t)row * D_ + col] = f2bf(acc[n][r] + bv);
            }
        }
    } else {
        // ---------------- V transpose: 2 l-tiles per block ----------------
        uint32_t* T = sm;
        const int vb = pid - 512;            // 0..255
        const int b  = vb >> 5;
        const int l0base = (vb & 31) * 64;
        const int r2 = tid >> 4;
        const int dg = tid & 15;
        const int lp = r2 ^ ((dg & 3) << 2);
#pragma unroll
        for (int it = 0; it < 2; it++) {
            const int l0 = l0base + it * 32;
            if (it) __syncthreads();
#pragma unroll
            for (int p = 0; p < 4; p++) {
                int d0 = (dg + p * 16) * 4;
                const float* src = V + ((size_t)b * L_ + l0 + r2 * 2) * D_ + d0;
                float4 e0 = *(const float4*)src;
                float4 e1 = *(const float4*)(src + D_);
                T[(d0 + 0) * 20 + lp] = pack2bf(e0.x, e1.x);
                T[(d0 + 1) * 20 + lp] = pack2bf(e0.y, e1.y);
                T[(d0 + 2) * 20 + lp] = pack2bf(e0.z, e1.z);
                T[(d0 + 3) * 20 + lp] = pack2bf(e0.w, e1.w);
            }
            __syncthreads();
#pragma unroll
            for (int p = 0; p < 4; p++) {
                int d = (tid >> 2) + p * 64;
                int c = tid & 3;
                int cp = c ^ ((d >> 2) & 3);
                uint4 u = *(const uint4*)&T[d * 20 + cp * 4];
                *(uint4*)(Vt + ((size_t)b * D_ + d) * L_ + l0 + c * 8) = u;
            }
        }
    }
}

// ---------------------------------------------------------------------------
// Flash (R2 structure): qtile 128, 4 waves x 32q, KTILE 32, K+V LDS dbuf.
// S computed transposed (K.Q^T) -> b64 Ps writes; mask via ballot bitmask;
// last z-block per (b,qtile) merges partials and normalizes (no norm kernel).
// ---------------------------------------------------------------------------
__global__ __launch_bounds__(256, 2) void flash_kernel(
    const short* __restrict__ Qb, const short* __restrict__ Kb,
    const short* __restrict__ Vt, const int* __restrict__ mask,
    float* __restrict__ Out, _Float16* __restrict__ Part,
    float* __restrict__ Lpart, int* __restrict__ Cnt)
{
    __shared__ short Ks[2][KTILE * 256];   // 2 x 16 KB
    __shared__ short Vs[2][256 * KTILE];   // 2 x 16 KB
    __shared__ short Ps[4 * 32 * PSS];     // 10 KB, per-wave private
    __shared__ int lastflag;

    const int tid  = threadIdx.x;
    const int wid  = tid >> 6;
    const int lane = tid & 63;
    const int m16  = lane & 15;
    const int quad = lane >> 4;
    const int b  = blockIdx.x;
    const int qy = blockIdx.y;
    const int q0 = qy * 128;
    const int z  = blockIdx.z;

    const short* kbase = Kb + ((size_t)b * L_ + z * KRANGE) * D_;
    const short* vbase = Vt + (size_t)b * D_ * L_ + (size_t)z * KRANGE;
    const int*   mg    = mask + b * L_ + z * KRANGE;

    // Q: 32 rows x 256 d per wave, register-resident (also used as B-operand)
    bf16x8 qf[2][8];
    {
        const short* qrow = Qb + ((size_t)b * L_ + q0 + wid * 32) * D_;
#pragma unroll
        for (int s2 = 0; s2 < 2; s2++)
#pragma unroll
            for (int kk = 0; kk < 8; kk++)
                qf[s2][kk] = *(const bf16x8*)(qrow + (size_t)(s2 * 16 + m16) * D_ + kk * 32 + quad * 8);
    }

    floatx4 o[2][16];
    const floatx4 z4 = {0.f, 0.f, 0.f, 0.f};
#pragma unroll
    for (int s2 = 0; s2 < 2; s2++)
#pragma unroll
        for (int n = 0; n < 16; n++) o[s2][n] = z4;
    float rsum[2] = {0.f, 0.f};

    auto stageK = [&](int t, int bufi) {
#pragma unroll
        for (int c = 0; c < 4; c++) {
            int unit = wid * 4 + c;
            int row = unit * 2 + (lane >> 5);
            int g = (lane & 31) ^ (row & 7);
            async16(kbase + (size_t)(t * KTILE + row) * D_ + g * 8,
                    &Ks[bufi][unit * 512]);
        }
    };
    auto stageV = [&](int t, int bufi) {
#pragma unroll
        for (int c = 0; c < 4; c++) {
            int unit = wid * 4 + c;
            int d = unit * 16 + (lane >> 2);
            int g = (lane & 3) ^ ((lane >> 2) & 3);
            async16(vbase + (size_t)d * L_ + t * KTILE + g * 8,
                    &Vs[bufi][unit * 512]);
        }
    };

    stageK(0, 0);
    stageV(0, 0);
    __builtin_amdgcn_s_waitcnt(0x0F70);  // vmcnt(0)
    __syncthreads();

    short* ps = Ps + wid * (32 * PSS);
    const float C2 = 0.09016844f;        // log2(e)/16
    unsigned long long mb = 0;

    for (int t = 0; t < NITER; t++) {
        const int buf = t & 1;
        if (t + 1 < NITER) { stageK(t + 1, buf ^ 1); stageV(t + 1, buf ^ 1); }

        int mvv = 0;
        if ((t & 1) == 0) mvv = mg[t * KTILE + lane];   // covers iters t, t+1

        // ---- S^T = K . Q^T : tiles [j(k-half)][s2(q-strip)] ----
        const short* kl = &Ks[buf][0];
        floatx4 sT[2][2];
        sT[0][0] = z4; sT[0][1] = z4; sT[1][0] = z4; sT[1][1] = z4;
#pragma unroll
        for (int kk = 0; kk < 8; kk++) {
            int lc = (kk * 4 + quad) ^ (m16 & 7);
            bf16x8 kf0 = *(const bf16x8*)(kl + m16 * 256 + lc * 8);
            bf16x8 kf1 = *(const bf16x8*)(kl + (16 + m16) * 256 + lc * 8);
            sT[0][0] = __builtin_amdgcn_mfma_f32_16x16x32_bf16(kf0, qf[0][kk], sT[0][0], 0, 0, 0);
            sT[0][1] = __builtin_amdgcn_mfma_f32_16x16x32_bf16(kf0, qf[1][kk], sT[0][1], 0, 0, 0);
            sT[1][0] = __builtin_amdgcn_mfma_f32_16x16x32_bf16(kf1, qf[0][kk], sT[1][0], 0, 0, 0);
            sT[1][1] = __builtin_amdgcn_mfma_f32_16x16x32_bf16(kf1, qf[1][kk], sT[1][1], 0, 0, 0);
        }

        // ---- masked exp, Ps write (b64), row-sums ----
        if ((t & 1) == 0) mb = __ballot(mvv != 0);
        const int sh = ((t & 1) << 5) + quad * 4;
#pragma unroll
        for (int j = 0; j < 2; j++) {
            const uint32_t nib = (uint32_t)(mb >> (sh + j * 16)) & 0xFu;
#pragma unroll
            for (int s2 = 0; s2 < 2; s2++) {
                float p0 = (nib & 1u) ? exp2f(sT[j][s2][0] * C2) : 0.f;
                float p1 = (nib & 2u) ? exp2f(sT[j][s2][1] * C2) : 0.f;
                float p2 = (nib & 4u) ? exp2f(sT[j][s2][2] * C2) : 0.f;
                float p3 = (nib & 8u) ? exp2f(sT[j][s2][3] * C2) : 0.f;
                rsum[s2] += (p0 + p1) + (p2 + p3);
                uint2 w; w.x = pack2bf(p0, p1); w.y = pack2bf(p2, p3);
                *(uint2*)(ps + (s2 * 16 + m16) * PSS + j * 16 + quad * 4) = w;
            }
        }
        __builtin_amdgcn_s_waitcnt(0xC07F);  // lgkmcnt(0): own Ps writes visible
        bf16x8 pf0 = *(const bf16x8*)(ps + m16 * PSS + quad * 8);
        bf16x8 pf1 = *(const bf16x8*)(ps + (16 + m16) * PSS + quad * 8);

        // ---- O += P V ----
        const short* vl = &Vs[buf][0];
#pragma unroll
        for (int n = 0; n < 16; n++) {
            int rowd = n * 16 + m16;
            int cidx = quad ^ (m16 & 3);
            bf16x8 vf = *(const bf16x8*)(vl + rowd * 32 + cidx * 8);
            o[0][n] = __builtin_amdgcn_mfma_f32_16x16x32_bf16(pf0, vf, o[0][n], 0, 0, 0);
            o[1][n] = __builtin_amdgcn_mfma_f32_16x16x32_bf16(pf1, vf, o[1][n], 0, 0, 0);
        }

        __builtin_amdgcn_s_waitcnt(0x0F70);  // vmcnt(0): next-tile DMA landed
        __syncthreads();
    }

    // ---- finalize row sums (reduce across quads) ----
#pragma unroll
    for (int s2 = 0; s2 < 2; s2++) {
        float x = rsum[s2];
        x += __shfl_xor(x, 16);
        x += __shfl_xor(x, 32);
        rsum[s2] = x;
    }
    const int BL = B_ * L_;
    const size_t rowb = (size_t)b * L_ + q0 + wid * 32;
    if (lane < 16) {
#pragma unroll
        for (int s2 = 0; s2 < 2; s2++)
            Lpart[(size_t)z * BL + rowb + s2 * 16 + lane] = rsum[s2];
    }

    // ---- store partial O ----
    const size_t BLD = (size_t)B_ * L_ * D_;
    if (z == 0) {
        float* po = Out + rowb * D_;
#pragma unroll
        for (int s2 = 0; s2 < 2; s2++)
#pragma unroll
            for (int n = 0; n < 16; n++)
#pragma unroll
                for (int r = 0; r < 4; r++)
                    po[(size_t)(s2 * 16 + quad * 4 + r) * D_ + n * 16 + m16] = o[s2][n][r];
    } else {
        _Float16* pp = Part + (size_t)(z - 1) * BLD + rowb * D_;
#pragma unroll
        for (int s2 = 0; s2 < 2; s2++)
#pragma unroll
            for (int n = 0; n < 16; n++)
#pragma unroll
                for (int r = 0; r < 4; r++)
                    pp[(size_t)(s2 * 16 + quad * 4 + r) * D_ + n * 16 + m16] = (_Float16)o[s2][n][r];
    }

    // ---- last z-block for this (b,qtile) merges + normalizes ----
    __threadfence();
    if (tid == 0) lastflag = (atomicAdd(&Cnt[b * 16 + qy], 1) == KSPLIT - 1);
    __syncthreads();
    if (!lastflag) return;
    __threadfence();

    const size_t rbase = (size_t)b * L_ + q0;
    for (int i = tid; i < 128 * 64; i += 256) {
        const int row = i >> 6;
        const int c4  = (i & 63) * 4;
        const size_t off = (rbase + row) * D_ + c4;
        float4 a = *(float4*)(Out + off);
#pragma unroll
        for (int zz = 0; zz < 3; zz++) {
            half4_t h = *(const half4_t*)(Part + zz * BLD + off);
            a.x += (float)h.x; a.y += (float)h.y;
            a.z += (float)h.z; a.w += (float)h.w;
        }
        const size_t rr = rbase + row;
        float l = Lpart[rr] + Lpart[BL + rr] + Lpart[2 * BL + rr] + Lpart[3 * BL + rr];
        float inv = 1.0f / l;
        a.x *= inv; a.y *= inv; a.z *= inv; a.w *= inv;
        *(float4*)(Out + off) = a;
    }
}

extern "C" void kernel_launch(void* const* d_in, const int* in_sizes, int n_in,
                              void* d_out, int out_size, void* d_ws, size_t ws_size,
                              hipStream_t stream) {
    const float* query = (const float*)d_in[0];
    const float* key   = (const float*)d_in[1];
    const float* value = (const float*)d_in[2];
    const int*   mask  = (const int*)d_in[3];
    const float* Wq_w  = (const float*)d_in[4];
    const float* Wq_b  = (const float*)d_in[5];
    const float* Wk_w  = (const float*)d_in[6];
    const float* Wk_b  = (const float*)d_in[7];
    float* out = (float*)d_out;

    const size_t BLD = (size_t)B_ * L_ * D_;
    short* qb = (short*)d_ws;
    short* kb = qb + BLD;
    short* vt = kb + BLD;
    _Float16* part = (_Float16*)(vt + BLD);      // 3 * BLD halves
    float* lpart = (float*)(part + 3 * BLD);     // 4 * B*L floats
    int* cnt = (int*)(lpart + (size_t)4 * B_ * L_);  // 128 ints

    hipMemsetAsync(cnt, 0, 128 * sizeof(int), stream);
    prep_kernel<<<dim3(768), 256, 0, stream>>>(query, key, value, Wq_w, Wk_w,
                                               Wq_b, Wk_b, qb, kb, vt);
    flash_kernel<<<dim3(8, 16, 4), 256, 0, stream>>>(qb, kb, vt, mask, out,
                                                     part, lpart, cnt);
}